// Round 2
// baseline (570.990 us; speedup 1.0000x reference)
//
#include <hip/hip_runtime.h>
#include <hip/hip_cooperative_groups.h>

// HybridSatelliteNormalizer: per-(B,C) channel percentile normalization.
// x: (16,3,1024,1024) fp32. 48 channels x 1,048,576 px each.
//
// Exact k-th-value selection via 2-level histogram (1024 coarse x 1024 fine
// = 2^20 virtual bins), then apply.
//
// This revision: ONE cooperative kernel (grid=768 = 3 blocks/CU, guaranteed
// co-resident) with 2 grid.sync()s replacing the hist/refine/apply dispatch
// chain. Purpose: (a) remove remaining inter-dispatch serialization, (b) make
// phase C's re-read of each block's own chunk L3-hot, (c) produce ONE
// profiler row with real FETCH/WRITE/VALUBusy for our code — every top-5 row
// so far has been a harness fill, leaving us blind.

namespace cg = cooperative_groups;

#define HW (1024 * 1024)
#define NCH 48
#define BPC 16
#define GRID_C (NCH * BPC)                   // 768 blocks = 3 blocks/CU exact
#define F4_PER_BLOCK (HW / BPC / 4)          // 16384 float4 per block
#define F4_PER_THREAD (F4_PER_BLOCK / 256)   // 64 per thread
#define UNROLL 8

typedef float f32x4 __attribute__((ext_vector_type(4)));

// Inclusive prefix-scan of g[0..1023] into LDS s[0..1023]; part = LDS[256]
// temp. 256 threads; ends with a barrier. Safe to call repeatedly with the
// same LDS buffers: callers' reads of s from a prior call all happen before
// this call's internal barriers, and s is rewritten only after those.
__device__ __forceinline__ void scan1024(const unsigned* __restrict__ g,
                                         unsigned* __restrict__ s,
                                         unsigned* __restrict__ part) {
    const int t = threadIdx.x;
    const uint4 gv = ((const uint4*)g)[t];
    const unsigned p01 = gv.x + gv.y;
    const unsigned p012 = p01 + gv.z;
    const unsigned sum = p012 + gv.w;
    part[t] = sum;
    __syncthreads();
    for (int off = 1; off < 256; off <<= 1) {
        unsigned q = (t >= off) ? part[t - off] : 0u;
        __syncthreads();
        part[t] += q;
        __syncthreads();
    }
    const unsigned excl = (t == 0) ? 0u : part[t - 1];
    s[4 * t + 0] = excl + gv.x;
    s[4 * t + 1] = excl + p01;
    s[4 * t + 2] = excl + p012;
    s[4 * t + 3] = excl + sum;
    __syncthreads();
}

__device__ __forceinline__ float apply_one(float xx, float mn, float isc,
                                           float mean, float istd) {
    float y = (xx - mn) * isc;
    y = fminf(fmaxf(y, 0.0f), 1.0f);
    // y^(1/2.2) via hw log2/exp2; exactly 0 at y==0 like the reference
    const float g = 0.45454547f;
    float p = (y > 0.0f) ? exp2f(g * log2f(y)) : 0.0f;
    return (p - mean) * istd;
}

__global__ __launch_bounds__(256, 3) void k_fused(
        const float* __restrict__ x, float* __restrict__ out,
        unsigned* __restrict__ hist, unsigned* __restrict__ sub2,
        unsigned* __restrict__ sub98) {
    __shared__ unsigned lh[1024];
    __shared__ unsigned s[1024];
    __shared__ unsigned part[256];
    __shared__ int sb2, sr2, sb98, sr98, sf2, sf98;

    const int t = threadIdx.x;
    const int ch = (int)blockIdx.x / BPC;
    const long long base = (long long)blockIdx.x * F4_PER_BLOCK;
    const f32x4* __restrict__ xv = (const f32x4*)x + base;

    // ---------------- Phase A: coarse 1024-bin histogram ----------------
    for (int i = t; i < 1024; i += 256) lh[i] = 0u;
    __syncthreads();
    for (int i = 0; i < F4_PER_THREAD; i += UNROLL) {
        f32x4 v[UNROLL];
#pragma unroll
        for (int u = 0; u < UNROLL; ++u) v[u] = xv[(i + u) * 256 + t];
#pragma unroll
        for (int u = 0; u < UNROLL; ++u) {
#pragma unroll
            for (int k = 0; k < 4; ++k) {
                const float f = v[u][k];
                if (f > 1e-4f) {
                    int j = (int)(f * 1048576.0f);
                    j = min(j, 1048575);
                    atomicAdd(&lh[j >> 10], 1u);
                }
            }
        }
    }
    __syncthreads();
    unsigned* __restrict__ gh = hist + ch * 1024;
    for (int i = t; i < 1024; i += 256) {
        const unsigned c = lh[i];
        if (c) atomicAdd(&gh[i], c);  // device-scope by default
    }

    cg::this_grid().sync();

    // ---------------- Phase B: coarse select + fine sub-histograms ------
    if (t == 0) { sb2 = -2; sr2 = 0; sb98 = -2; sr98 = 0; }  // ordered by scan's barriers
    scan1024(gh, s, part);
    const int n = (int)s[1023];  // block-uniform
    if (n > 0) {
        // reference: k = min(p*n//100 + 1, n); idx = k-1 -> min(p*n/100, n-1)
        const int i2 = min((2 * n) / 100, n - 1);
        const int i98 = min((98 * n) / 100, n - 1);  // 98n < 2^31, fits int32
#pragma unroll
        for (int q = 0; q < 4; ++q) {
            const int b = 4 * t + q;
            const unsigned excl = (b == 0) ? 0u : s[b - 1];
            const unsigned incl = s[b];
            if (excl <= (unsigned)i2 && (unsigned)i2 < incl) { sb2 = b; sr2 = i2 - (int)excl; }
            if (excl <= (unsigned)i98 && (unsigned)i98 < incl) { sb98 = b; sr98 = i98 - (int)excl; }
        }
    }
    __syncthreads();
    const int b2 = sb2, b98 = sb98;

    if (n > 0) {
        unsigned* __restrict__ g2 = sub2 + ch * 1024;
        unsigned* __restrict__ g98 = sub98 + ch * 1024;
        for (int i = 0; i < F4_PER_THREAD; i += UNROLL) {
            f32x4 v[UNROLL];
#pragma unroll
            for (int u = 0; u < UNROLL; ++u) v[u] = xv[(i + u) * 256 + t];
#pragma unroll
            for (int u = 0; u < UNROLL; ++u) {
#pragma unroll
                for (int k = 0; k < 4; ++k) {
                    const float f = v[u][k];
                    if (f > 1e-4f) {
                        int j = (int)(f * 1048576.0f);  // identical expr to phase A
                        j = min(j, 1048575);
                        const int cb = j >> 10, fb = j & 1023;
                        // ~64 hits/block/bin -> direct global atomics are cheap
                        if (cb == b2) atomicAdd(&g2[fb], 1u);
                        if (cb == b98) atomicAdd(&g98[fb], 1u);
                    }
                }
            }
        }
    }

    cg::this_grid().sync();

    // ---------------- Phase C: fine select + apply ----------------------
    if (t == 0) { sf2 = 0; sf98 = 0; }
    if (n > 0) {
        scan1024(sub2 + ch * 1024, s, part);
        const int r2 = sr2;
#pragma unroll
        for (int q = 0; q < 4; ++q) {
            const int b = 4 * t + q;
            const unsigned excl = (b == 0) ? 0u : s[b - 1];
            const unsigned incl = s[b];
            if (excl <= (unsigned)r2 && (unsigned)r2 < incl) sf2 = b;
        }
        scan1024(sub98 + ch * 1024, s, part);  // barrier discipline protects s
        const int r98 = sr98;
#pragma unroll
        for (int q = 0; q < 4; ++q) {
            const int b = 4 * t + q;
            const unsigned excl = (b == 0) ? 0u : s[b - 1];
            const unsigned incl = s[b];
            if (excl <= (unsigned)r98 && (unsigned)r98 < incl) sf98 = b;
        }
    }
    __syncthreads();

    const bool use = n > 100;
    float mn, isc;
    if (use) {
        const float v2 = ((float)(b2 * 1024 + sf2) + 0.5f) * (1.0f / 1048576.0f);
        const float v98 = ((float)(b98 * 1024 + sf98) + 0.5f) * (1.0f / 1048576.0f);
        mn = v2;
        isc = 1.0f / fmaxf(v98 - v2, 1e-6f);
    } else {
        mn = 0.0f;
        isc = 1.0f;  // 1/max(1-0, 1e-6)
    }
    const int c3 = ch % 3;
    // explicit selects, not a runtime-indexed array (avoid scratch)
    const float mean = (c3 == 0) ? 0.485f : (c3 == 1) ? 0.456f : 0.406f;
    const float istd = (c3 == 0) ? (1.0f / 0.229f)
                      : (c3 == 1) ? (1.0f / 0.224f) : (1.0f / 0.225f);

    f32x4* __restrict__ ov = (f32x4*)out + base;
    for (int i = 0; i < F4_PER_THREAD; i += UNROLL) {
        f32x4 v[UNROLL];
#pragma unroll
        for (int u = 0; u < UNROLL; ++u) v[u] = xv[(i + u) * 256 + t];
#pragma unroll
        for (int u = 0; u < UNROLL; ++u) {
            f32x4 r;
            r.x = apply_one(v[u].x, mn, isc, mean, istd);
            r.y = apply_one(v[u].y, mn, isc, mean, istd);
            r.z = apply_one(v[u].z, mn, isc, mean, istd);
            r.w = apply_one(v[u].w, mn, isc, mean, istd);
            __builtin_nontemporal_store(r, &ov[(i + u) * 256 + t]);
        }
    }
}

extern "C" void kernel_launch(void* const* d_in, const int* in_sizes, int n_in,
                              void* d_out, int out_size, void* d_ws, size_t ws_size,
                              hipStream_t stream) {
    const float* x = (const float*)d_in[0];
    float* out = (float*)d_out;

    // workspace: hist 48*1024 u32 | sub2 48*1024 u32 | sub98 48*1024 u32
    unsigned* hist = (unsigned*)d_ws;
    unsigned* sub2 = hist + NCH * 1024;
    unsigned* sub98 = sub2 + NCH * 1024;
    const size_t ws_used = (size_t)(3 * NCH * 1024) * 4;

    hipMemsetAsync(d_ws, 0, ws_used, stream);

    void* args[] = {(void*)&x, (void*)&out, (void*)&hist, (void*)&sub2,
                    (void*)&sub98};
    hipLaunchCooperativeKernel((void*)k_fused, dim3(GRID_C), dim3(256), args,
                               0, stream);
}

// Round 3
// 403.598 us; speedup vs baseline: 1.4147x; 1.4147x over previous
//
#include <hip/hip_runtime.h>

// HybridSatelliteNormalizer: per-(B,C) channel percentile normalization.
// x: (16,3,1024,1024) fp32. 48 channels x 1,048,576 px each.
//
// Exact k-th-value selection via 2-level histogram (1024 coarse x 1024 fine
// = 2^20 virtual bins), then a streaming apply pass.
//
// Round-2 profile of the fused variant: HBM 18%, VALU 14%, occupancy 35%,
// LDS conflicts ~2% -> latency-bound, nothing saturated. This revision goes
// back to split dispatches (coop launch cost ~220us of harness overhead) and
// attacks occupancy: BPC=64 -> grid 3072 (8 blocks/CU resident = 32 waves/CU,
// the HW max) with __launch_bounds__(256,8) capping VGPR at 64 (round-2
// kernels used 36). refine publishes selection state to an info buffer so
// apply skips the coarse scan; apply uses nontemporal loads (last reader of
// x) and nontemporal stores (out is never re-read).

#define HW (1024 * 1024)
#define NCH 48
#define BPC 64
#define GRID_STREAM (NCH * BPC)              // 3072 blocks = 12 rounds of 8/CU
#define F4_PER_BLOCK (HW / BPC / 4)          // 4096 float4 per block
#define F4_PER_THREAD (F4_PER_BLOCK / 256)   // 16 per thread
#define UNROLL 8

typedef float f32x4 __attribute__((ext_vector_type(4)));

// Inclusive prefix-scan of g[0..1023] into LDS s[0..1023]; part = LDS[256]
// temp. 256 threads; ends with a barrier. Safe to call repeatedly with the
// same LDS buffers: callers' reads of s from a prior call all happen before
// this call's internal barriers, and s is rewritten only after those.
__device__ __forceinline__ void scan1024(const unsigned* __restrict__ g,
                                         unsigned* __restrict__ s,
                                         unsigned* __restrict__ part) {
    const int t = threadIdx.x;
    const uint4 gv = ((const uint4*)g)[t];
    const unsigned p01 = gv.x + gv.y;
    const unsigned p012 = p01 + gv.z;
    const unsigned sum = p012 + gv.w;
    part[t] = sum;
    __syncthreads();
    for (int off = 1; off < 256; off <<= 1) {
        unsigned q = (t >= off) ? part[t - off] : 0u;
        __syncthreads();
        part[t] += q;
        __syncthreads();
    }
    const unsigned excl = (t == 0) ? 0u : part[t - 1];
    s[4 * t + 0] = excl + gv.x;
    s[4 * t + 1] = excl + p01;
    s[4 * t + 2] = excl + p012;
    s[4 * t + 3] = excl + sum;
    __syncthreads();
}

// ---------------- Pass A: coarse histogram (LDS, then global atomics) -------
__global__ __launch_bounds__(256, 8) void k_hist(const float* __restrict__ x,
                                                 unsigned* __restrict__ hist) {
    __shared__ unsigned lh[1024];
    const int t = threadIdx.x;
    for (int i = t; i < 1024; i += 256) lh[i] = 0u;
    __syncthreads();

    const int ch = (int)blockIdx.x / BPC;
    const long long base = (long long)blockIdx.x * F4_PER_BLOCK;
    const f32x4* __restrict__ xv = (const f32x4*)x + base;

    for (int i = 0; i < F4_PER_THREAD; i += UNROLL) {
        f32x4 v[UNROLL];
#pragma unroll
        for (int u = 0; u < UNROLL; ++u) v[u] = xv[(i + u) * 256 + t];
#pragma unroll
        for (int u = 0; u < UNROLL; ++u) {
#pragma unroll
            for (int k = 0; k < 4; ++k) {
                const float f = v[u][k];
                if (f > 1e-4f) {
                    int j = (int)(f * 1048576.0f);
                    j = min(j, 1048575);
                    atomicAdd(&lh[j >> 10], 1u);
                }
            }
        }
    }
    __syncthreads();
    unsigned* __restrict__ gh = hist + ch * 1024;
    for (int i = t; i < 1024; i += 256) {
        const unsigned c = lh[i];
        if (c) atomicAdd(&gh[i], c);
    }
}

// ---------------- Pass B: coarse select + fine sub-histograms ---------------
__global__ __launch_bounds__(256, 8) void k_refine(const float* __restrict__ x,
                                                   const unsigned* __restrict__ hist,
                                                   unsigned* __restrict__ sub2,
                                                   unsigned* __restrict__ sub98,
                                                   int* __restrict__ info) {
    __shared__ unsigned s[1024];
    __shared__ unsigned part[256];
    __shared__ int sb2, sr2, sb98, sr98;
    const int t = threadIdx.x;
    const int ch = (int)blockIdx.x / BPC;
    if (t == 0) { sb2 = -2; sr2 = 0; sb98 = -2; sr98 = 0; }  // ordered by scan's barriers

    scan1024(hist + ch * 1024, s, part);
    const int n = (int)s[1023];  // block-uniform
    if (n > 0) {
        // reference: k = min(p*n//100 + 1, n); idx = k-1 -> min(p*n/100, n-1)
        const int i2 = min((2 * n) / 100, n - 1);
        const int i98 = min((98 * n) / 100, n - 1);  // 98n < 2^31, fits int32
#pragma unroll
        for (int q = 0; q < 4; ++q) {
            const int b = 4 * t + q;
            const unsigned excl = (b == 0) ? 0u : s[b - 1];
            const unsigned incl = s[b];
            if (excl <= (unsigned)i2 && (unsigned)i2 < incl) { sb2 = b; sr2 = i2 - (int)excl; }
            if (excl <= (unsigned)i98 && (unsigned)i98 < incl) { sb98 = b; sr98 = i98 - (int)excl; }
        }
    }
    __syncthreads();
    const int b2 = sb2, b98 = sb98;

    // one block per channel publishes selection state for k_apply (all blocks
    // of a channel compute identical values from the same hist)
    if (((int)blockIdx.x % BPC) == 0 && t == 0) {
        info[ch * 8 + 0] = n;
        info[ch * 8 + 1] = b2;
        info[ch * 8 + 2] = sr2;
        info[ch * 8 + 3] = b98;
        info[ch * 8 + 4] = sr98;
    }

    if (n > 0) {
        const long long base = (long long)blockIdx.x * F4_PER_BLOCK;
        const f32x4* __restrict__ xv = (const f32x4*)x + base;
        unsigned* __restrict__ g2 = sub2 + ch * 1024;
        unsigned* __restrict__ g98 = sub98 + ch * 1024;
        for (int i = 0; i < F4_PER_THREAD; i += UNROLL) {
            f32x4 v[UNROLL];
#pragma unroll
            for (int u = 0; u < UNROLL; ++u) v[u] = xv[(i + u) * 256 + t];
#pragma unroll
            for (int u = 0; u < UNROLL; ++u) {
#pragma unroll
                for (int k = 0; k < 4; ++k) {
                    const float f = v[u][k];
                    if (f > 1e-4f) {
                        int j = (int)(f * 1048576.0f);  // identical expr to pass A
                        j = min(j, 1048575);
                        const int cb = j >> 10, fb = j & 1023;
                        // ~16 hits/block/bin -> direct global atomics are cheap
                        if (cb == b2) atomicAdd(&g2[fb], 1u);
                        if (cb == b98) atomicAdd(&g98[fb], 1u);
                    }
                }
            }
        }
    }
}

// ---------------- Pass C: fine select + apply -------------------------------
__device__ __forceinline__ float apply_one(float xx, float mn, float isc,
                                           float mean, float istd) {
    float y = (xx - mn) * isc;
    y = fminf(fmaxf(y, 0.0f), 1.0f);
    // y^(1/2.2) via hw log2/exp2; exactly 0 at y==0 like the reference
    const float g = 0.45454547f;
    float p = (y > 0.0f) ? exp2f(g * log2f(y)) : 0.0f;
    return (p - mean) * istd;
}

__global__ __launch_bounds__(256, 8) void k_apply(const float* __restrict__ x,
                                                  float* __restrict__ out,
                                                  const unsigned* __restrict__ sub2,
                                                  const unsigned* __restrict__ sub98,
                                                  const int* __restrict__ info) {
    __shared__ unsigned s[1024];
    __shared__ unsigned part[256];
    __shared__ int sf2, sf98;
    const int t = threadIdx.x;
    const int ch = (int)blockIdx.x / BPC;

    const int n = info[ch * 8 + 0];
    const int b2 = info[ch * 8 + 1], r2 = info[ch * 8 + 2];
    const int b98 = info[ch * 8 + 3], r98 = info[ch * 8 + 4];
    if (t == 0) { sf2 = 0; sf98 = 0; }  // ordered by scan's barriers

    if (n > 0) {
        scan1024(sub2 + ch * 1024, s, part);
#pragma unroll
        for (int q = 0; q < 4; ++q) {
            const int b = 4 * t + q;
            const unsigned excl = (b == 0) ? 0u : s[b - 1];
            const unsigned incl = s[b];
            if (excl <= (unsigned)r2 && (unsigned)r2 < incl) sf2 = b;
        }
        scan1024(sub98 + ch * 1024, s, part);  // barrier discipline protects s
#pragma unroll
        for (int q = 0; q < 4; ++q) {
            const int b = 4 * t + q;
            const unsigned excl = (b == 0) ? 0u : s[b - 1];
            const unsigned incl = s[b];
            if (excl <= (unsigned)r98 && (unsigned)r98 < incl) sf98 = b;
        }
    }
    __syncthreads();

    const bool use = n > 100;
    float mn, isc;
    if (use) {
        const float v2 = ((float)(b2 * 1024 + sf2) + 0.5f) * (1.0f / 1048576.0f);
        const float v98 = ((float)(b98 * 1024 + sf98) + 0.5f) * (1.0f / 1048576.0f);
        mn = v2;
        isc = 1.0f / fmaxf(v98 - v2, 1e-6f);
    } else {
        mn = 0.0f;
        isc = 1.0f;  // 1/max(1-0, 1e-6)
    }
    const int c3 = ch % 3;
    // explicit selects, not a runtime-indexed array (avoid scratch)
    const float mean = (c3 == 0) ? 0.485f : (c3 == 1) ? 0.456f : 0.406f;
    const float istd = (c3 == 0) ? (1.0f / 0.229f)
                      : (c3 == 1) ? (1.0f / 0.224f) : (1.0f / 0.225f);

    const long long base = (long long)blockIdx.x * F4_PER_BLOCK;
    const f32x4* __restrict__ xv = (const f32x4*)x + base;
    f32x4* __restrict__ ov = (f32x4*)out + base;

    for (int i = 0; i < F4_PER_THREAD; i += UNROLL) {
        f32x4 v[UNROLL];
#pragma unroll
        for (int u = 0; u < UNROLL; ++u)
            v[u] = __builtin_nontemporal_load(&xv[(i + u) * 256 + t]);
#pragma unroll
        for (int u = 0; u < UNROLL; ++u) {
            f32x4 r;
            r.x = apply_one(v[u].x, mn, isc, mean, istd);
            r.y = apply_one(v[u].y, mn, isc, mean, istd);
            r.z = apply_one(v[u].z, mn, isc, mean, istd);
            r.w = apply_one(v[u].w, mn, isc, mean, istd);
            __builtin_nontemporal_store(r, &ov[(i + u) * 256 + t]);
        }
    }
}

extern "C" void kernel_launch(void* const* d_in, const int* in_sizes, int n_in,
                              void* d_out, int out_size, void* d_ws, size_t ws_size,
                              hipStream_t stream) {
    const float* x = (const float*)d_in[0];
    float* out = (float*)d_out;

    // workspace: hist 48*1024 u32 | sub2 48*1024 u32 | sub98 48*1024 u32
    //          | info 48*8 int {n, b2, r2, b98, r98, -, -, -}
    unsigned* hist = (unsigned*)d_ws;
    unsigned* sub2 = hist + NCH * 1024;
    unsigned* sub98 = sub2 + NCH * 1024;
    int* info = (int*)(sub98 + NCH * 1024);
    const size_t ws_zero = (size_t)(3 * NCH * 1024) * 4;  // info fully overwritten

    hipMemsetAsync(d_ws, 0, ws_zero, stream);
    k_hist<<<GRID_STREAM, 256, 0, stream>>>(x, hist);
    k_refine<<<GRID_STREAM, 256, 0, stream>>>(x, hist, sub2, sub98, info);
    k_apply<<<GRID_STREAM, 256, 0, stream>>>(x, out, sub2, sub98, info);
}